// Round 2
// baseline (796.227 us; speedup 1.0000x reference)
//
#include <hip/hip_runtime.h>
#include <hip/hip_bf16.h>

// Problem constants
constexpr int Bc  = 4;
constexpr int Sc  = 2048;
constexpr int Dc  = 1024;
constexpr int Hc  = 16;
constexpr int DKc = 64;
constexpr int Mc  = Bc * Sc;      // 8192 token rows

typedef __bf16 bf16x8 __attribute__((ext_vector_type(8)));
typedef float  f32x4  __attribute__((ext_vector_type(4)));

#define DEV __device__ __forceinline__

DEV unsigned short f2bf(float f) {
    unsigned u = __builtin_bit_cast(unsigned, f);
    u += 0x7FFFu + ((u >> 16) & 1u);            // RNE
    return (unsigned short)(u >> 16);
}
DEV unsigned pack2(float a, float b) {
    return (unsigned)f2bf(a) | ((unsigned)f2bf(b) << 16);
}

// ---------------------------------------------------------------------------
// Fold na_w into projection weights: out[h*DK+i][j] = sum_t na[i][t]*w[h*DK+t][j]
__global__ __launch_bounds__(256) void fold_w(const float* __restrict__ na,
                                              const float* __restrict__ w,
                                              unsigned short* __restrict__ out) {
    int idx = blockIdx.x * 256 + threadIdx.x;   // 0 .. D*D-1
    int col = idx & (Dc - 1);
    int row = idx >> 10;
    int h = row >> 6, i = row & 63;
    float acc = 0.f;
#pragma unroll 8
    for (int t = 0; t < DKc; ++t)
        acc += na[i * DKc + t] * w[(h * DKc + t) * Dc + col];
    out[idx] = f2bf(acc);
}

__global__ __launch_bounds__(256) void conv_w(const float* __restrict__ w,
                                              unsigned short* __restrict__ out) {
    int i = blockIdx.x * 256 + threadIdx.x;
    out[i] = f2bf(w[i]);
}

__global__ __launch_bounds__(256) void fold_b(const float* __restrict__ na,
                                              const float* __restrict__ b,
                                              const float* __restrict__ nb,
                                              float* __restrict__ out) {
    int idx = blockIdx.x * 256 + threadIdx.x;
    if (idx >= Dc) return;
    int h = idx >> 6, i = idx & 63;
    float acc = nb[i];
    for (int t = 0; t < DKc; ++t) acc += na[i * DKc + t] * b[h * DKc + t];
    out[idx] = acc;
}

// Pack int32 mask -> bitmask (bit=1 keep). One thread per element, ballot per wave.
__global__ __launch_bounds__(256) void pack_mask(const int* __restrict__ m,
                                                 unsigned* __restrict__ out) {
    size_t gid = (size_t)blockIdx.x * 256 + threadIdx.x;
    int v = m[gid];
    unsigned long long bal = __ballot(v != 0);
    int lane = threadIdx.x & 63;
    if (lane == 0)       out[gid >> 5] = (unsigned)bal;
    else if (lane == 32) out[gid >> 5] = (unsigned)(bal >> 32);
}

// ---------------------------------------------------------------------------
// Generic 128x128x(K) GEMM, C = A * B^T (+bias, epilogue variants).
// A: [M,K] (fp32 or bf16), B: [N,K] (fp32 or bf16). 4 waves, 64x64 per wave,
// 16x16x32 bf16 MFMA, BK=64, reg-staged LDS with XOR swizzle both sides.
// EPI 0: tanh(acc+bias[col]) -> bf16 head layout [B,H,S,DK]
// EPI 1: acc+bias[row]       -> bf16 vT layout   [B,H,DK,S]   (rows are weight-n)
// EPI 2: acc+bias[col]       -> fp32 merged      [M,N]
template <bool AF32, bool BF32, int EPI>
__global__ __launch_bounds__(256) void gemm_k(const void* __restrict__ Ap,
                                              const void* __restrict__ Bp,
                                              const float* __restrict__ bias,
                                              void* __restrict__ outp,
                                              int Mdim, int Ndim, int Kdim) {
    constexpr int BK = 64;
    __shared__ unsigned char As[128 * 128];  // 128 rows x 128B (64 bf16)
    __shared__ unsigned char Bs[128 * 128];

    const int tid = threadIdx.x, lane = tid & 63, wave = tid >> 6;
    const int wr = wave >> 1, wc = wave & 1;
    const int m0 = blockIdx.y * 128, n0 = blockIdx.x * 128;

    f32x4 acc[4][4] = {};

    const int nK = Kdim / BK;
    for (int kt = 0; kt < nK; ++kt) {
        const int k0 = kt * BK;
        float4 afr[8]; uint4 abr[4];
        float4 bfr[8]; uint4 bbr[4];
        if constexpr (AF32) {
            const float* A = (const float*)Ap;
            const int c4 = tid & 15;
#pragma unroll
            for (int i = 0; i < 8; ++i) {
                int row = (tid >> 4) + 16 * i;
                afr[i] = *(const float4*)(A + (size_t)(m0 + row) * Kdim + k0 + c4 * 4);
            }
        } else {
            const unsigned short* A = (const unsigned short*)Ap;
            const int c8 = tid & 7;
#pragma unroll
            for (int i = 0; i < 4; ++i) {
                int row = (tid >> 3) + 32 * i;
                abr[i] = *(const uint4*)(A + (size_t)(m0 + row) * Kdim + k0 + c8 * 8);
            }
        }
        if constexpr (BF32) {
            const float* Bm = (const float*)Bp;
            const int c4 = tid & 15;
#pragma unroll
            for (int i = 0; i < 8; ++i) {
                int row = (tid >> 4) + 16 * i;
                bfr[i] = *(const float4*)(Bm + (size_t)(n0 + row) * Kdim + k0 + c4 * 4);
            }
        } else {
            const unsigned short* Bm = (const unsigned short*)Bp;
            const int c8 = tid & 7;
#pragma unroll
            for (int i = 0; i < 4; ++i) {
                int row = (tid >> 3) + 32 * i;
                bbr[i] = *(const uint4*)(Bm + (size_t)(n0 + row) * Kdim + k0 + c8 * 8);
            }
        }
        __syncthreads();   // previous tile's LDS reads complete
        if constexpr (AF32) {
            const int colb = (tid & 15) * 8;
#pragma unroll
            for (int i = 0; i < 8; ++i) {
                int row = (tid >> 4) + 16 * i;
                uint2 u; u.x = pack2(afr[i].x, afr[i].y); u.y = pack2(afr[i].z, afr[i].w);
                *(uint2*)(As + row * 128 + (colb ^ ((row & 7) << 4))) = u;
            }
        } else {
            const int colb = (tid & 7) * 16;
#pragma unroll
            for (int i = 0; i < 4; ++i) {
                int row = (tid >> 3) + 32 * i;
                *(uint4*)(As + row * 128 + (colb ^ ((row & 7) << 4))) = abr[i];
            }
        }
        if constexpr (BF32) {
            const int colb = (tid & 15) * 8;
#pragma unroll
            for (int i = 0; i < 8; ++i) {
                int row = (tid >> 4) + 16 * i;
                uint2 u; u.x = pack2(bfr[i].x, bfr[i].y); u.y = pack2(bfr[i].z, bfr[i].w);
                *(uint2*)(Bs + row * 128 + (colb ^ ((row & 7) << 4))) = u;
            }
        } else {
            const int colb = (tid & 7) * 16;
#pragma unroll
            for (int i = 0; i < 4; ++i) {
                int row = (tid >> 3) + 32 * i;
                *(uint4*)(Bs + row * 128 + (colb ^ ((row & 7) << 4))) = bbr[i];
            }
        }
        __syncthreads();
#pragma unroll
        for (int s = 0; s < 2; ++s) {
            const int cb = s * 64 + (lane >> 4) * 16;
            bf16x8 a[4], b[4];
#pragma unroll
            for (int m = 0; m < 4; ++m) {
                int row = wr * 64 + m * 16 + (lane & 15);
                a[m] = *(const bf16x8*)(As + row * 128 + (cb ^ ((row & 7) << 4)));
            }
#pragma unroll
            for (int n = 0; n < 4; ++n) {
                int row = wc * 64 + n * 16 + (lane & 15);
                b[n] = *(const bf16x8*)(Bs + row * 128 + (cb ^ ((row & 7) << 4)));
            }
#pragma unroll
            for (int m = 0; m < 4; ++m)
#pragma unroll
                for (int n = 0; n < 4; ++n)
                    acc[m][n] = __builtin_amdgcn_mfma_f32_16x16x32_bf16(a[m], b[n], acc[m][n], 0, 0, 0);
        }
    }

    // Epilogue. C/D layout: row=(lane>>4)*4+r, col=lane&15 (m89-verified).
#pragma unroll
    for (int m = 0; m < 4; ++m)
#pragma unroll
        for (int n = 0; n < 4; ++n)
#pragma unroll
            for (int r = 0; r < 4; ++r) {
                int gm = m0 + wr * 64 + m * 16 + ((lane >> 4) << 2) + r;
                int gn = n0 + wc * 64 + n * 16 + (lane & 15);
                float v = acc[m][n][r];
                if constexpr (EPI == 0) {
                    v = tanhf(v + bias[gn]);
                    int b = gm >> 11, s = gm & 2047, hh = gn >> 6, dk = gn & 63;
                    ((unsigned short*)outp)[(((size_t)(b * Hc + hh)) * Sc + s) * DKc + dk] = f2bf(v);
                } else if constexpr (EPI == 1) {
                    v += bias[gm];
                    int hh = gm >> 6, dk = gm & 63, b = gn >> 11, s = gn & 2047;
                    ((unsigned short*)outp)[(((size_t)(b * Hc + hh)) * DKc + dk) * Sc + s] = f2bf(v);
                } else {
                    v += bias[gn];
                    ((float*)outp)[(size_t)gm * Ndim + gn] = v;
                }
            }
}

// ---------------------------------------------------------------------------
// Flash attention. Grid (S/64, H, B), 256 threads (4 waves, 16 q-rows each).
// Swapped QK^T (mfma(K,Q)): lane owns q-COLUMN q=lane&15 for softmax stats;
// the PV accumulator rows are q=(lane>>4)*4+r, so per-row alpha/l must be
// shuffled from lane q (the round-1 bug was scaling ctxa by lane&15's alpha).
__global__ __launch_bounds__(256) void attn_k(const unsigned short* __restrict__ qn,
                                              const unsigned short* __restrict__ kn,
                                              const unsigned short* __restrict__ vt,
                                              const unsigned* __restrict__ mbits,
                                              const float* __restrict__ temp,
                                              unsigned short* __restrict__ ctxb) {
    __shared__ unsigned char kns[128 * 128];    // [k:128][dk:64] bf16
    __shared__ unsigned char vts[64 * 256];     // [d:64][k:128] bf16
    __shared__ unsigned char Ps[4][16 * 256];   // per wave [q:16][k:128] bf16

    const int tid = threadIdx.x, lane = tid & 63, wave = tid >> 6;
    const int qt = blockIdx.x, h = blockIdx.y, b = blockIdx.z;
    const int q0 = qt * 64;
    const float scale = 1.f / (8.f * temp[h]);
    const size_t headoff = ((size_t)(b * Hc + h)) * Sc * DKc;

    // Q fragments (B-operand), held for the whole block
    bf16x8 qf[2];
    {
        const unsigned short* p = qn + headoff + (size_t)(q0 + wave * 16 + (lane & 15)) * DKc + ((lane >> 4) << 3);
        qf[0] = *(const bf16x8*)(p);
        qf[1] = *(const bf16x8*)(p + 32);
    }
    const unsigned* mrow = mbits + ((size_t)b * Sc + (q0 + wave * 16 + (lane & 15))) * (Sc / 32);

    f32x4 ctxa[4] = {};
    float m_run = -INFINITY, l_run = 0.f;

    for (int kt = 0; kt < Sc / 128; ++kt) {
        uint4 kreg[4], vreg[4];
        {
            const int c8 = tid & 7;
#pragma unroll
            for (int i = 0; i < 4; ++i) {
                int row = (tid >> 3) + 32 * i;
                kreg[i] = *(const uint4*)(kn + headoff + (size_t)(kt * 128 + row) * DKc + c8 * 8);
            }
        }
        {
            const int c16 = tid & 15;
#pragma unroll
            for (int i = 0; i < 4; ++i) {
                int row = (tid >> 4) + 16 * i;
                vreg[i] = *(const uint4*)(vt + headoff + (size_t)row * Sc + kt * 128 + c16 * 8);
            }
        }
        unsigned mw[4];
#pragma unroll
        for (int j = 0; j < 4; ++j) mw[j] = mrow[kt * 4 + j];

        __syncthreads();
        {
            const int colb = (tid & 7) * 16;
#pragma unroll
            for (int i = 0; i < 4; ++i) {
                int row = (tid >> 3) + 32 * i;
                *(uint4*)(kns + row * 128 + (colb ^ ((row & 7) << 4))) = kreg[i];
            }
        }
        {
            const int colb = (tid & 15) * 16;
#pragma unroll
            for (int i = 0; i < 4; ++i) {
                int row = (tid >> 4) + 16 * i;
                *(uint4*)(vts + row * 256 + (colb ^ ((row & 7) << 4))) = vreg[i];
            }
        }
        __syncthreads();

        // scores^T[k][q]
        f32x4 sc[8] = {};
#pragma unroll
        for (int s = 0; s < 2; ++s) {
            const int cb = s * 64 + (lane >> 4) * 16;
#pragma unroll
            for (int f = 0; f < 8; ++f) {
                int row = f * 16 + (lane & 15);
                bf16x8 a = *(const bf16x8*)(kns + row * 128 + (cb ^ ((row & 7) << 4)));
                sc[f] = __builtin_amdgcn_mfma_f32_16x16x32_bf16(a, qf[s], sc[f], 0, 0, 0);
            }
        }

        // mask + scale + online softmax (lane owns q = lane&15, 32 k values)
        float pv[8][4];
        float tmax = -INFINITY;
#pragma unroll
        for (int f = 0; f < 8; ++f) {
            unsigned w = mw[f >> 1];
#pragma unroll
            for (int r = 0; r < 4; ++r) {
                int bit = ((f & 1) << 4) + ((lane >> 4) << 2) + r;
                float s = sc[f][r] * scale;
                s = ((w >> bit) & 1u) ? s : -1e9f;
                pv[f][r] = s;
                tmax = fmaxf(tmax, s);
            }
        }
        tmax = fmaxf(tmax, __shfl_xor(tmax, 16));
        tmax = fmaxf(tmax, __shfl_xor(tmax, 32));
        float newm = fmaxf(m_run, tmax);
        float alpha = __expf(m_run - newm);
        float tsum = 0.f;
#pragma unroll
        for (int f = 0; f < 8; ++f)
#pragma unroll
            for (int r = 0; r < 4; ++r) {
                float e = __expf(pv[f][r] - newm);
                pv[f][r] = e;
                tsum += e;
            }
        tsum += __shfl_xor(tsum, 16);
        tsum += __shfl_xor(tsum, 32);
        l_run = l_run * alpha + tsum;
        m_run = newm;

        // FIX: ctxa[j][r] holds q = (lane>>4)*4+r, not q = lane&15.
        // Fetch the alpha of the accumulator's own q row before rescaling.
        float al[4];
#pragma unroll
        for (int r = 0; r < 4; ++r) al[r] = __shfl(alpha, ((lane >> 4) << 2) + r);
#pragma unroll
        for (int j = 0; j < 4; ++j)
#pragma unroll
            for (int r = 0; r < 4; ++r) ctxa[j][r] *= al[r];

        // write P (bf16) to per-wave LDS [q][k]; reg pairs are k-adjacent
        {
            unsigned char* pb = Ps[wave];
            const int row = lane & 15;
            const int swz = (row & 7) << 4;
#pragma unroll
            for (int f = 0; f < 8; ++f) {
                int cb0 = f * 32 + ((lane >> 4) << 3);
                *(unsigned*)(pb + row * 256 + (cb0 ^ swz))       = pack2(pv[f][0], pv[f][1]);
                *(unsigned*)(pb + row * 256 + ((cb0 + 4) ^ swz)) = pack2(pv[f][2], pv[f][3]);
            }
        }
        __syncthreads();

        // PV: ctx[q][d] += P[q][k] * V[k][d]
#pragma unroll
        for (int cs = 0; cs < 4; ++cs) {
            const int cb = cs * 64 + (lane >> 4) * 16;
            const int rowp = lane & 15;
            bf16x8 pa = *(const bf16x8*)(Ps[wave] + rowp * 256 + (cb ^ ((rowp & 7) << 4)));
#pragma unroll
            for (int j = 0; j < 4; ++j) {
                int rowv = j * 16 + (lane & 15);
                bf16x8 vb = *(const bf16x8*)(vts + rowv * 256 + (cb ^ ((rowv & 7) << 4)));
                ctxa[j] = __builtin_amdgcn_mfma_f32_16x16x32_bf16(pa, vb, ctxa[j], 0, 0, 0);
            }
        }
    }

    // epilogue: divide by row-sum (per accumulator row's q), write merged bf16 ctx
    float lv[4];
#pragma unroll
    for (int r = 0; r < 4; ++r) lv[r] = __shfl(l_run, ((lane >> 4) << 2) + r);
#pragma unroll
    for (int j = 0; j < 4; ++j)
#pragma unroll
        for (int r = 0; r < 4; ++r) {
            int srow = q0 + wave * 16 + ((lane >> 4) << 2) + r;
            int col = h * DKc + j * 16 + (lane & 15);
            float v = ctxa[j][r] / lv[r];
            ctxb[((size_t)b * Sc + srow) * Dc + col] = f2bf(v);
        }
}

// ---------------------------------------------------------------------------
__global__ __launch_bounds__(256) void rmsnorm_k(float* __restrict__ out,
                                                 const float* __restrict__ w) {
    const int row = blockIdx.x, tid = threadIdx.x;
    float4* p = (float4*)(out + (size_t)row * Dc) + tid;
    float4 v = *p;
    float ss = v.x * v.x + v.y * v.y + v.z * v.z + v.w * v.w;
#pragma unroll
    for (int o = 32; o >= 1; o >>= 1) ss += __shfl_xor(ss, o);
    __shared__ float sm[4];
    if ((tid & 63) == 0) sm[tid >> 6] = ss;
    __syncthreads();
    float tot = sm[0] + sm[1] + sm[2] + sm[3];
    float r = rsqrtf(tot * (1.f / Dc) + 1e-8f);
    float4 wv = *((const float4*)w + tid);
    v.x *= r * wv.x; v.y *= r * wv.y; v.z *= r * wv.z; v.w *= r * wv.w;
    *p = v;
}

// ---------------------------------------------------------------------------
extern "C" void kernel_launch(void* const* d_in, const int* in_sizes, int n_in,
                              void* d_out, int out_size, void* d_ws, size_t ws_size,
                              hipStream_t stream) {
    (void)in_sizes; (void)n_in; (void)out_size; (void)ws_size;
    const float* Q    = (const float*)d_in[0];
    const float* K    = (const float*)d_in[1];
    const float* V    = (const float*)d_in[2];
    const int*   mask = (const int*)  d_in[3];
    const float* wq   = (const float*)d_in[4];
    const float* bq   = (const float*)d_in[5];
    const float* wk   = (const float*)d_in[6];
    const float* bk   = (const float*)d_in[7];
    const float* wv   = (const float*)d_in[8];
    const float* bv   = (const float*)d_in[9];
    const float* wo   = (const float*)d_in[10];
    const float* bo   = (const float*)d_in[11];
    const float* naqw = (const float*)d_in[12];
    const float* naqb = (const float*)d_in[13];
    const float* nakw = (const float*)d_in[14];
    const float* nakb = (const float*)d_in[15];
    const float* temp = (const float*)d_in[16];
    const float* rmsw = (const float*)d_in[17];

    char* ws = (char*)d_ws;
    size_t off = 0;
    auto take = [&](size_t n) { char* p = ws + off; off += (n + 255) & ~(size_t)255; return p; };
    unsigned short* qnb  = (unsigned short*)take((size_t)Mc * Dc * 2);
    unsigned short* knb  = (unsigned short*)take((size_t)Mc * Dc * 2);
    unsigned short* vtb  = (unsigned short*)take((size_t)Mc * Dc * 2);
    unsigned short* ctxb = (unsigned short*)take((size_t)Mc * Dc * 2);
    unsigned short* wqf  = (unsigned short*)take((size_t)Dc * Dc * 2);
    unsigned short* wkf  = (unsigned short*)take((size_t)Dc * Dc * 2);
    unsigned short* wvf  = (unsigned short*)take((size_t)Dc * Dc * 2);
    unsigned short* wof  = (unsigned short*)take((size_t)Dc * Dc * 2);
    float*    bqf   = (float*)take(Dc * 4);
    float*    bkf   = (float*)take(Dc * 4);
    unsigned* mbits = (unsigned*)take((size_t)Bc * Sc * (Sc / 32) * 4);

    fold_w<<<dim3(Dc * Dc / 256), 256, 0, stream>>>(naqw, wq, wqf);
    fold_w<<<dim3(Dc * Dc / 256), 256, 0, stream>>>(nakw, wk, wkf);
    conv_w<<<dim3(Dc * Dc / 256), 256, 0, stream>>>(wv, wvf);
    conv_w<<<dim3(Dc * Dc / 256), 256, 0, stream>>>(wo, wof);
    fold_b<<<dim3((Dc + 255) / 256), 256, 0, stream>>>(naqw, bq, naqb, bqf);
    fold_b<<<dim3((Dc + 255) / 256), 256, 0, stream>>>(nakw, bk, nakb, bkf);
    pack_mask<<<dim3(Bc * Sc * Sc / 256), 256, 0, stream>>>(mask, mbits);

    // qn = tanh(Q @ Wq'^T + bq')  (bf16, [B,H,S,DK]);  same for kn
    gemm_k<true, false, 0><<<dim3(Dc / 128, Mc / 128), 256, 0, stream>>>(Q, wqf, bqf, qnb, Mc, Dc, Dc);
    gemm_k<true, false, 0><<<dim3(Dc / 128, Mc / 128), 256, 0, stream>>>(K, wkf, bkf, knb, Mc, Dc, Dc);
    // v^T = Wv @ V_in^T + bv  (bf16, [B,H,DK,S])
    gemm_k<false, true, 1><<<dim3(Mc / 128, Dc / 128), 256, 0, stream>>>(wvf, V, bv, vtb, Dc, Mc, Dc);

    attn_k<<<dim3(Sc / 64, Hc, Bc), 256, 0, stream>>>(qnb, knb, vtb, mbits, temp, ctxb);

    // out = ctx @ wo^T + bo (fp32 into d_out), then in-place RMSNorm
    gemm_k<false, false, 2><<<dim3(Dc / 128, Mc / 128), 256, 0, stream>>>(ctxb, wof, bo, d_out, Mc, Dc, Dc);
    rmsnorm_k<<<dim3(Mc), 256, 0, stream>>>((float*)d_out, rmsw);
}